// Round 1
// 129.458 us; speedup vs baseline: 1.0120x; 1.0120x over previous
//
#include <hip/hip_runtime.h>
#include <math.h>

typedef __bf16 bf16x8 __attribute__((ext_vector_type(8)));
typedef float  f32x4  __attribute__((ext_vector_type(4)));
typedef int    i32x4  __attribute__((ext_vector_type(4)));

#define MFMA16(a, b, c) __builtin_amdgcn_mfma_f32_16x16x32_bf16((a), (b), (c), 0, 0, 0)

// A-tile: row stride 128 elements, 16B chunks XOR-swizzled by row (16-row
// reads hit each bank-pair 2-way = free per m136).
#define ATIDX(r, c) ((r) * 128 + (((c) ^ ((r) & 7)) * 8))

// ---------------------------------------------------------------------------
// setup: merged xpose + prep, now fully vectorized (float4 in / bf16x8 out;
// weight prep 8 elems/thread so the store is one coalesced 16B write).
// ---------------------------------------------------------------------------
__global__ __launch_bounds__(256) void setup_kernel(
    const float* __restrict__ x, const float* __restrict__ w,
    const float* __restrict__ w_off, const float* __restrict__ bconv,
    const float* __restrict__ gamma, const float* __restrict__ beta,
    const float* __restrict__ mean, const float* __restrict__ var,
    __bf16* __restrict__ xT, __bf16* __restrict__ wFragD,
    __bf16* __restrict__ wFragO, float* __restrict__ sc,
    float* __restrict__ sh) {
  int t = threadIdx.x;
  if (blockIdx.x < 1024) {
    __shared__ float xs[64][65];
    int b = blockIdx.x >> 8, y = (blockIdx.x >> 2) & 63, cc = blockIdx.x & 3;
    const float* xb = x + (((size_t)b * 256 + cc * 64) * 64 + y) * 64;
    #pragma unroll
    for (int r = 0; r < 4; ++r) {
      int cl = r * 16 + (t >> 4), xc = (t & 15) * 4;
      f32x4 v = *(const f32x4*)(xb + (size_t)cl * 4096 + xc);
      xs[cl][xc] = v.x; xs[cl][xc + 1] = v.y;
      xs[cl][xc + 2] = v.z; xs[cl][xc + 3] = v.w;
    }
    __syncthreads();
    __bf16* dst = xT + (((size_t)b * 64 + y) * 64) * 256 + cc * 64;
    #pragma unroll
    for (int it = 0; it < 2; ++it) {
      int w2 = t + it * 256;
      int xc = w2 >> 3, cl8 = (w2 & 7) * 8;
      bf16x8 o;
      #pragma unroll
      for (int e = 0; e < 8; ++e) o[e] = (__bf16)xs[cl8 + e][xc];
      *(bf16x8*)(dst + (size_t)xc * 256 + cl8) = o;
    }
    return;
  }
  if (blockIdx.x < 1312) {                 // wFragD: 288 blocks, 8 elems/thr
    int u = (blockIdx.x - 1024) * 256 + t; // 0..73727
    int lane = u & 63, ocb = (u >> 6) & 15, kc = (u >> 10) & 3, gk = u >> 12;
    int oc = ocb * 16 + (lane & 15);
    int cb = kc * 32 + (lane >> 4) * 8;
    int g = gk / 9, ktap = gk % 9;
    const float* src = w + ((size_t)oc * 256 + g * 128 + cb) * 9 + ktap;
    bf16x8 o;
    #pragma unroll
    for (int j = 0; j < 8; ++j) o[j] = (__bf16)src[(size_t)j * 9];
    *(bf16x8*)(wFragD + (size_t)u * 8) = o;
    return;
  }
  if (blockIdx.x < 1384) {                 // wFragO: 72 blocks, 8 elems/thr
    int u = (blockIdx.x - 1312) * 256 + t; // 0..18431
    int lane = u & 63, ocq = (u >> 6) & 3, kc = (u >> 8) & 7, tap = u >> 11;
    int oc = ocq * 16 + (lane & 15);
    int cb = kc * 32 + (lane >> 4) * 8;
    bf16x8 o;
    #pragma unroll
    for (int j = 0; j < 8; ++j) o[j] = (__bf16)0.f;
    if (oc < 54) {
      const float* src = w_off + ((size_t)oc * 256 + cb) * 9 + tap;
      #pragma unroll
      for (int j = 0; j < 8; ++j) o[j] = (__bf16)src[(size_t)j * 9];
    }
    *(bf16x8*)(wFragO + (size_t)u * 8) = o;
    return;
  }
  if (t < 256) {
    float s = gamma[t] * rsqrtf(var[t] + 1e-5f);
    sc[t] = s;
    sh[t] = (bconv[t] - mean[t]) * s + beta[t];
  }
}

// ---------------------------------------------------------------------------
// fused kernel — now 1024 threads (16 waves = 4/SIMD) to double latency
// hiding; per-wave tile halves (16 oc), schedule/pipeline unchanged.
// Offset-conv splits K across wave pairs (kh) with LDS partial reduction.
// ---------------------------------------------------------------------------
struct PhaseC {
  f32x4 swgtv[18 * 64];
  i32x4 slinv[18 * 64];
  __bf16 atile[2][2][64 * 128];   // [buf][tap-in-pair][...]
};
union FusedLDS {
  __bf16 rowbuf[3 * 66 * 256];
  PhaseC c;
};

__global__ __launch_bounds__(1024) void fused_kernel(
    const __bf16* __restrict__ xT, const __bf16* __restrict__ wFragD,
    const __bf16* __restrict__ wFragO, const float* __restrict__ b_off,
    const float* __restrict__ sc, const float* __restrict__ sh,
    float* __restrict__ out) {
  __shared__ __attribute__((aligned(16))) FusedLDS U;
  __shared__ float omrow[2][54 * 64];
  int t = threadIdx.x;
  int b = blockIdx.x >> 6, y = blockIdx.x & 63;
  int lane = t & 63, wv = t >> 6;          // wv in 0..15
  int l15 = lane & 15, quad = lane >> 4;
  const __bf16* xTb = xT + (size_t)b * 64 * 64 * 256;
  bf16x8 z8;
  #pragma unroll
  for (int e = 0; e < 8; ++e) z8[e] = (__bf16)0.f;

  // ---- phase A: stage rowbuf[dy][px66][ch] ----
  for (int i = t; i < 3 * 66 * 32; i += 1024) {
    int c = i & 31, px66 = (i >> 5) % 66, dy = i / 2112;
    int y2 = y + dy - 1, x2 = px66 - 1;
    bf16x8 v = z8;
    if (y2 >= 0 && y2 < 64 && x2 >= 0 && x2 < 64)
      v = *(const bf16x8*)(xTb + ((size_t)y2 * 64 + x2) * 256 + c * 8);
    *(bf16x8*)&U.rowbuf[dy * 16896 + px66 * 256 + ((c ^ (px66 & 7)) * 8)] = v;
  }
  __syncthreads();

  // offset-conv: 9 taps pure MFMA from rowbuf; K split across kh wave-pairs
  {
    int kh = wv & 1, ocq = (wv >> 1) & 3, mh = wv >> 3;
    f32x4 acc0 = {0.f, 0.f, 0.f, 0.f};
    f32x4 acc1 = {0.f, 0.f, 0.f, 0.f};
    for (int tap = 0; tap < 9; ++tap) {
      int dy = tap / 3, dxs = tap % 3;
      const __bf16* bb =
          wFragO + ((size_t)(tap * 8 + kh * 4) * 4 + ocq) * 512 + lane * 8;
      bf16x8 Bf[4];
      #pragma unroll
      for (int kcl = 0; kcl < 4; ++kcl)
        Bf[kcl] = *(const bf16x8*)(bb + (size_t)kcl * 4 * 512);
      int p0 = mh * 32 + l15 + dxs, p1 = p0 + 16;
      const __bf16* rb = U.rowbuf + dy * 16896;
      #pragma unroll
      for (int kcl = 0; kcl < 4; ++kcl) {
        int c = (kh * 4 + kcl) * 4 + quad;
        bf16x8 a0 = *(const bf16x8*)&rb[p0 * 256 + ((c ^ (p0 & 7)) * 8)];
        bf16x8 a1 = *(const bf16x8*)&rb[p1 * 256 + ((c ^ (p1 & 7)) * 8)];
        acc0 = MFMA16(a0, Bf[kcl], acc0);
        acc1 = MFMA16(a1, Bf[kcl], acc1);
      }
    }
    int oc = ocq * 16 + l15;
    if (oc < 54) {
      #pragma unroll
      for (int fm = 0; fm < 2; ++fm) {
        f32x4 v = fm ? acc1 : acc0;
        int pxs = mh * 32 + fm * 16 + quad * 4;
        *(f32x4*)&omrow[kh][oc * 64 + pxs] = v;
      }
    }
  }
  __syncthreads();                        // omrow ready; rowbuf dead

  // ---- phase B: sum K-partials (+bias) -> bilinear corner tables ----
  for (int i = t; i < 18 * 64; i += 1024) {
    int gk = i >> 6, p = i & 63;
    int k = gk % 9;
    float oy = omrow[0][gk * 64 + p] + omrow[1][gk * 64 + p] + b_off[gk];
    float ox = omrow[0][(18 + gk) * 64 + p] + omrow[1][(18 + gk) * 64 + p]
             + b_off[18 + gk];
    float mz = omrow[0][(36 + gk) * 64 + p] + omrow[1][(36 + gk) * 64 + p]
             + b_off[36 + gk];
    float mv = 1.f / (1.f + expf(-mz));
    float py  = (float)(y + (k / 3) - 1) + oy;
    float pxf = (float)(p + (k % 3) - 1) + ox;
    float y0f = floorf(py), x0f = floorf(pxf);
    int y0 = (int)y0f, x0 = (int)x0f;
    float ly = py - y0f, lx = pxf - x0f;
    int y1 = y0 + 1, x1 = x0 + 1;
    bool vy0 = (y0 >= 0) && (y0 < 64), vy1 = (y1 >= 0) && (y1 < 64);
    bool vx0 = (x0 >= 0) && (x0 < 64), vx1 = (x1 >= 0) && (x1 < 64);
    int cy0 = min(max(y0, 0), 63), cy1 = min(max(y1, 0), 63);
    int cx0 = min(max(x0, 0), 63), cx1 = min(max(x1, 0), 63);
    f32x4 sv;
    sv.x = (vy0 && vx0) ? (1.f - ly) * (1.f - lx) * mv : 0.f;
    sv.y = (vy0 && vx1) ? (1.f - ly) * lx * mv : 0.f;
    sv.z = (vy1 && vx0) ? ly * (1.f - lx) * mv : 0.f;
    sv.w = (vy1 && vx1) ? ly * lx * mv : 0.f;
    i32x4 lv;
    lv.x = (cy0 * 64 + cx0) * 256;
    lv.y = (cy0 * 64 + cx1) * 256;
    lv.z = (cy1 * 64 + cx0) * 256;
    lv.w = (cy1 * 64 + cx1) * 256;
    U.c.swgtv[i] = sv;
    U.c.slinv[i] = lv;
  }

  f32x4 acc[4];
  #pragma unroll
  for (int fm = 0; fm < 4; ++fm) acc[fm] = (f32x4){0.f, 0.f, 0.f, 0.f};

  __syncthreads();                        // tables visible; rowbuf region free

  int ch0 = l15 * 8;
  int p = wv * 4 + quad;                  // each thread owns one (p, chunk)
  // prologue: gather taps 0 and 1 directly into atile[0][0/1]
  #pragma unroll
  for (int t2 = 0; t2 < 2; ++t2) {
    const __bf16* xg = xTb + ch0;         // taps 0,1 are group 0
    f32x4 sv = U.c.swgtv[t2 * 64 + p];
    i32x4 lv = U.c.slinv[t2 * 64 + p];
    bf16x8 c0 = *(const bf16x8*)(xg + lv.x);
    bf16x8 c1 = *(const bf16x8*)(xg + lv.y);
    bf16x8 c2 = *(const bf16x8*)(xg + lv.z);
    bf16x8 c3 = *(const bf16x8*)(xg + lv.w);
    bf16x8 o;
    #pragma unroll
    for (int e = 0; e < 8; ++e)
      o[e] = (__bf16)(sv.x * (float)c0[e] + sv.y * (float)c1[e]
                    + sv.z * (float)c2[e] + sv.w * (float)c3[e]);
    *(bf16x8*)&U.c.atile[0][t2][ATIDX(p, l15)] = o;
  }

  // ---- phase C main loop: 9 intervals of 2 taps ----
  for (int iv = 0; iv < 9; ++iv) {
    __syncthreads();                      // atile[iv&1][*] ready
    // B-frags for taps 2iv, 2iv+1 — issued FIRST (oldest in vmcnt queue)
    bf16x8 Bf0[4], Bf1[4];
    {
      const __bf16* bb0 =
          wFragD + ((size_t)(2 * iv) * 4 * 16 + wv) * 512 + lane * 8;
      const __bf16* bb1 = bb0 + (size_t)4 * 16 * 512;
      #pragma unroll
      for (int kc = 0; kc < 4; ++kc)
        Bf0[kc] = *(const bf16x8*)(bb0 + (size_t)kc * 16 * 512);
      #pragma unroll
      for (int kc = 0; kc < 4; ++kc)
        Bf1[kc] = *(const bf16x8*)(bb1 + (size_t)kc * 16 * 512);
    }
    // gathers for taps 2iv+2, 2iv+3 (in flight across the MFMA section)
    bf16x8 cr[2][4];
    f32x4 sv[2];
    if (iv < 8) {
      #pragma unroll
      for (int t2 = 0; t2 < 2; ++t2) {
        int gn = 2 * iv + 2 + t2;
        const __bf16* xg = xTb + (gn / 9) * 128 + ch0;
        sv[t2] = U.c.swgtv[gn * 64 + p];
        i32x4 lv = U.c.slinv[gn * 64 + p];
        cr[t2][0] = *(const bf16x8*)(xg + lv.x);
        cr[t2][1] = *(const bf16x8*)(xg + lv.y);
        cr[t2][2] = *(const bf16x8*)(xg + lv.z);
        cr[t2][3] = *(const bf16x8*)(xg + lv.w);
      }
    }
    __builtin_amdgcn_sched_barrier(0);    // pin: loads above, MFMA below
    {
      const __bf16* at0 = U.c.atile[iv & 1][0];
      #pragma unroll
      for (int kc = 0; kc < 4; ++kc) {
        #pragma unroll
        for (int fm = 0; fm < 4; ++fm) {
          bf16x8 a = *(const bf16x8*)&at0[ATIDX(fm * 16 + l15, kc * 4 + quad)];
          acc[fm] = MFMA16(a, Bf0[kc], acc[fm]);
        }
      }
      const __bf16* at1 = U.c.atile[iv & 1][1];
      #pragma unroll
      for (int kc = 0; kc < 4; ++kc) {
        #pragma unroll
        for (int fm = 0; fm < 4; ++fm) {
          bf16x8 a = *(const bf16x8*)&at1[ATIDX(fm * 16 + l15, kc * 4 + quad)];
          acc[fm] = MFMA16(a, Bf1[kc], acc[fm]);
        }
      }
    }
    __builtin_amdgcn_sched_barrier(0);    // keep convert/writes below MFMA
    if (iv < 8) {
      #pragma unroll
      for (int t2 = 0; t2 < 2; ++t2) {
        __bf16* dst = U.c.atile[(iv + 1) & 1][t2];
        bf16x8 o;
        #pragma unroll
        for (int e = 0; e < 8; ++e)
          o[e] = (__bf16)(sv[t2].x * (float)cr[t2][0][e]
                        + sv[t2].y * (float)cr[t2][1][e]
                        + sv[t2].z * (float)cr[t2][2][e]
                        + sv[t2].w * (float)cr[t2][3][e]);
        *(bf16x8*)&dst[ATIDX(p, l15)] = o;
      }
    }
  }

  {
    int oc = wv * 16 + l15;
    float s = sc[oc], h = sh[oc];
    #pragma unroll
    for (int fm = 0; fm < 4; ++fm) {
      f32x4 v = acc[fm];
      f32x4 r = {fmaxf(v.x * s + h, 0.f), fmaxf(v.y * s + h, 0.f),
                 fmaxf(v.z * s + h, 0.f), fmaxf(v.w * s + h, 0.f)};
      int pxs = fm * 16 + quad * 4;
      *(f32x4*)(out + (((size_t)b * 256 + oc) * 64 + y) * 64 + pxs) = r;
    }
  }
}

// ---------------------------------------------------------------------------
extern "C" void kernel_launch(void* const* d_in, const int* in_sizes, int n_in,
                              void* d_out, int out_size, void* d_ws, size_t ws_size,
                              hipStream_t stream) {
  const float* x     = (const float*)d_in[0];
  const float* w_off = (const float*)d_in[1];
  const float* b_off = (const float*)d_in[2];
  const float* w     = (const float*)d_in[3];
  const float* bconv = (const float*)d_in[4];
  const float* gamma = (const float*)d_in[5];
  const float* beta  = (const float*)d_in[6];
  const float* rmean = (const float*)d_in[7];
  const float* rvar  = (const float*)d_in[8];
  float* out = (float*)d_out;

  __bf16* xT     = (__bf16*)d_ws;                          // 8,388,608 B
  __bf16* wFragD = (__bf16*)((char*)d_ws + 8388608);       // 1,179,648 B
  __bf16* wFragO = (__bf16*)((char*)d_ws + 9568256);       //   294,912 B
  float*  sc     = (float*)((char*)d_ws + 9863168);
  float*  sh     = (float*)((char*)d_ws + 9864192);

  setup_kernel<<<1385, 256, 0, stream>>>(
      x, w, w_off, bconv, gamma, beta, rmean, rvar, xT, wFragD, wFragO, sc, sh);
  fused_kernel<<<4 * 64, 1024, 0, stream>>>(xT, wFragD, wFragO, b_off, sc, sh, out);
}